// Round 1
// baseline (1499.967 us; speedup 1.0000x reference)
//
#include <hip/hip_runtime.h>
#include <hip/hip_bf16.h>
#include <math.h>

#define M_ 4096            // B*S
#define N_ 6144            // H*E
#define K_ 768             // H
#define H_ 768
#define L_ 2

using bf16x8 = __attribute__((ext_vector_type(8))) short;
using f32x4  = __attribute__((ext_vector_type(4))) float;

__device__ __forceinline__ unsigned short f2bf(float f) {
  unsigned int u = __builtin_bit_cast(unsigned int, f);
  u += 0x7FFFu + ((u >> 16) & 1u);
  return (unsigned short)(u >> 16);
}

__device__ __forceinline__ float gelu_exact(float x) {
  return 0.5f * x * (1.0f + erff(x * 0.70710678118654752f));
}

// async global->LDS, 16B per lane. LDS dest must be wave-uniform base; HW adds lane*16.
__device__ __forceinline__ void gload_lds16(const void* g, void* l) {
  __builtin_amdgcn_global_load_lds(
      (__attribute__((address_space(1))) unsigned int*)(uintptr_t)g,
      (__attribute__((address_space(3))) unsigned int*)(unsigned int)(uintptr_t)l,
      16, 0, 0);
}

// ---------------------------------------------------------------- prep kernels
__global__ __launch_bounds__(256) void copy3(const float4* __restrict__ a,
                                             const float4* __restrict__ b,
                                             const float4* __restrict__ c,
                                             float4* __restrict__ h) {
  const int n4 = M_ * H_ / 4;  // 786432
  int i = blockIdx.x * 256 + threadIdx.x;
  if (i < n4) h[i] = a[i];
  else if (i < 2 * n4) h[i] = b[i - n4];
  else h[i] = c[i - 2 * n4];
}

// W_exp [6][768(k)][6144(n)] fp32 -> Wb [6][6144(n)][768(k)] bf16  (LDS-tiled transpose)
__global__ __launch_bounds__(256) void conv_w(const float* __restrict__ W,
                                              short* __restrict__ Wb) {
  __shared__ float tile[64][65];
  const int z = blockIdx.z;            // l*3+t
  const int n0 = blockIdx.x * 64;
  const int k0 = blockIdx.y * 64;
  const size_t inb  = (size_t)z * K_ * N_;
  const size_t outb = (size_t)z * N_ * K_;
  const int tid = threadIdx.x;
  const int c = tid & 63;
  const int r = tid >> 6;              // 0..3
#pragma unroll
  for (int p = 0; p < 16; ++p) {
    const int kk = p * 4 + r;
    tile[c][kk] = W[inb + (size_t)(k0 + kk) * N_ + n0 + c];
  }
  __syncthreads();
#pragma unroll
  for (int p = 0; p < 16; ++p) {
    const int nn = p * 4 + r;
    Wb[outb + (size_t)(n0 + nn) * K_ + k0 + c] = (short)f2bf(tile[nn][c]);
  }
}

// ---------------------------------------------------------- LN + gates (1 wave/row)
__global__ __launch_bounds__(256, 4) void ln_gates(
    const float* __restrict__ h,      // [3][M][H]
    short* __restrict__ xs,           // [3][M][H] bf16 out
    const float* __restrict__ ln_g,   // [3][H] (layer offset applied by host)
    const float* __restrict__ ln_b,
    const float* __restrict__ Wg_sh,  // [H][24]
    const float* __restrict__ bg_sh,  // [24]
    const float* __restrict__ Wg_t1,  // [H][16]
    const float* __restrict__ bg_t1,
    const float* __restrict__ Wg_t2,
    const float* __restrict__ bg_t2,
    float* __restrict__ gates)        // g_sh [M][24] @0 ; g_t1 [M][16] @M*24 ; g_t2 @M*24+M*16
{
  const int gw   = blockIdx.x * 4 + (threadIdx.x >> 6);  // 0..12287
  const int t    = gw >> 12;                             // tower
  const int row  = gw & 4095;
  const int lane = threadIdx.x & 63;
  const float* hrow = h + ((size_t)t * M_ + row) * H_;

  float x[12];
  float sum = 0.f, ss = 0.f;
#pragma unroll
  for (int q = 0; q < 3; ++q) {
    float4 v = *(const float4*)(hrow + q * 256 + lane * 4);
    x[q * 4 + 0] = v.x; x[q * 4 + 1] = v.y; x[q * 4 + 2] = v.z; x[q * 4 + 3] = v.w;
    sum += v.x + v.y + v.z + v.w;
    ss  += v.x * v.x + v.y * v.y + v.z * v.z + v.w * v.w;
  }
#pragma unroll
  for (int m = 1; m < 64; m <<= 1) { sum += __shfl_xor(sum, m); ss += __shfl_xor(ss, m); }
  const float mean = sum * (1.f / 768.f);
  float var = ss * (1.f / 768.f) - mean * mean;
  var = var < 0.f ? 0.f : var;
  const float rstd = rsqrtf(var + 1e-5f);

  const float* ga = ln_g + (size_t)t * H_;
  const float* be = ln_b + (size_t)t * H_;
  short* xrow = xs + ((size_t)t * M_ + row) * H_;
#pragma unroll
  for (int q = 0; q < 3; ++q) {
    float4 g4 = *(const float4*)(ga + q * 256 + lane * 4);
    float4 b4 = *(const float4*)(be + q * 256 + lane * 4);
    float y0 = g4.x * (x[q * 4 + 0] - mean) * rstd + b4.x;
    float y1 = g4.y * (x[q * 4 + 1] - mean) * rstd + b4.y;
    float y2 = g4.z * (x[q * 4 + 2] - mean) * rstd + b4.z;
    float y3 = g4.w * (x[q * 4 + 3] - mean) * rstd + b4.w;
    x[q * 4 + 0] = y0; x[q * 4 + 1] = y1; x[q * 4 + 2] = y2; x[q * 4 + 3] = y3;
    ushort4 st; st.x = f2bf(y0); st.y = f2bf(y1); st.z = f2bf(y2); st.w = f2bf(y3);
    *(ushort4*)(xrow + q * 256 + lane * 4) = st;
  }

  // ---- gate logits for this tower ----
  const float* Wg; const float* bg;
  if (t == 0)      { Wg = Wg_sh; bg = bg_sh; }
  else if (t == 1) { Wg = Wg_t1; bg = bg_t1; }
  else             { Wg = Wg_t2; bg = bg_t2; }
  const int NG = (t == 0) ? 24 : 16;

  float p[24];
#pragma unroll
  for (int j = 0; j < 24; ++j) p[j] = 0.f;
#pragma unroll
  for (int q = 0; q < 3; ++q)
#pragma unroll
    for (int jj = 0; jj < 4; ++jj) {
      const int i = q * 256 + lane * 4 + jj;
      const float xv = x[q * 4 + jj];
      const float* wrow = Wg + (size_t)i * NG;
#pragma unroll
      for (int j = 0; j < 16; ++j) p[j] += xv * wrow[j];
      if (t == 0) {
#pragma unroll
        for (int j = 16; j < 24; ++j) p[j] += xv * wrow[j];
      }
    }
  // wave reduce
#pragma unroll
  for (int j = 0; j < 16; ++j)
#pragma unroll
    for (int m = 1; m < 64; m <<= 1) p[j] += __shfl_xor(p[j], m);
  if (t == 0) {
#pragma unroll
    for (int j = 16; j < 24; ++j)
#pragma unroll
      for (int m = 1; m < 64; m <<= 1) p[j] += __shfl_xor(p[j], m);
  }
  // bias + softmax (all lanes redundantly)
  float mx = -1e30f;
#pragma unroll
  for (int j = 0; j < 16; ++j) { p[j] += bg[j]; mx = fmaxf(mx, p[j]); }
  if (t == 0) {
#pragma unroll
    for (int j = 16; j < 24; ++j) { p[j] += bg[j]; mx = fmaxf(mx, p[j]); }
  }
  float s = 0.f;
#pragma unroll
  for (int j = 0; j < 16; ++j) { p[j] = expf(p[j] - mx); s += p[j]; }
  if (t == 0) {
#pragma unroll
    for (int j = 16; j < 24; ++j) { p[j] = expf(p[j] - mx); s += p[j]; }
  }
  const float inv = 1.f / s;

  float* grow;
  if (t == 0)      grow = gates + (size_t)row * 24;
  else if (t == 1) grow = gates + (size_t)M_ * 24 + (size_t)row * 16;
  else             grow = gates + (size_t)M_ * 24 + (size_t)M_ * 16 + (size_t)row * 16;
  if (lane == 0) {
#pragma unroll
    for (int j = 0; j < 16; ++j) grow[j] = p[j] * inv;
    if (t == 0) {
#pragma unroll
      for (int j = 16; j < 24; ++j) grow[j] = p[j] * inv;
    }
  }
}

// ------------------------------------------------ expert GEMM + gelu + gated combine
// A = xs[t] [M][K] bf16 ; Bt = Wb[t] [N][K] bf16 (pre-transposed) ; C-tile 128x128
__global__ __launch_bounds__(256, 2) void expert_gemm(
    const short* __restrict__ xs,      // [3][M][K]
    const short* __restrict__ Wb,      // [3][N][K] for this layer
    const float* __restrict__ b_exp_l, // [3][N]
    const float* __restrict__ g_sh,    // [M][24]
    const float* __restrict__ g_t1,    // [M][16]
    const float* __restrict__ g_t2,    // [M][16]
    float* __restrict__ h)             // [3][M][H]  (residual accumulate)
{
  const int t  = blockIdx.z;
  const int m0 = blockIdx.x * 128;
  const int n0 = blockIdx.y * 128;
  const short* A  = xs + (size_t)t * M_ * K_;
  const short* Bt = Wb + (size_t)t * N_ * K_;

  __shared__ short As[128 * 64];
  __shared__ short Bs[128 * 64];

  const int tid  = threadIdx.x;
  const int wave = tid >> 6;
  const int lane = tid & 63;
  const int wr = wave >> 1, wc = wave & 1;

  f32x4 acc[4][4];
#pragma unroll
  for (int i = 0; i < 4; ++i)
#pragma unroll
    for (int j = 0; j < 4; ++j) acc[i][j] = (f32x4){0.f, 0.f, 0.f, 0.f};

  const int lr8 = lane >> 3;  // 0..7
  const int seg = lane & 7;   // 0..7

  for (int kt = 0; kt < K_ / 64; ++kt) {
    __syncthreads();  // previous tile consumed
    const int k0 = kt * 64;
#pragma unroll
    for (int q = 0; q < 4; ++q) {
      const int rowbase = wave * 32 + q * 8;
      gload_lds16(A  + (size_t)(m0 + rowbase + lr8) * K_ + k0 + seg * 8, &As[rowbase * 64]);
      gload_lds16(Bt + (size_t)(n0 + rowbase + lr8) * K_ + k0 + seg * 8, &Bs[rowbase * 64]);
    }
    __syncthreads();  // staged tile visible (vmcnt drained by barrier)
    {
      const int lr = lane & 15;
#pragma unroll
      for (int ks = 0; ks < 2; ++ks) {
        const int lk = ks * 32 + ((lane >> 4) << 3);
        bf16x8 a[4], b[4];
#pragma unroll
        for (int mf = 0; mf < 4; ++mf)
          a[mf] = *(const bf16x8*)&As[(wr * 64 + mf * 16 + lr) * 64 + lk];
#pragma unroll
        for (int nf = 0; nf < 4; ++nf)
          b[nf] = *(const bf16x8*)&Bs[(wc * 64 + nf * 16 + lr) * 64 + lk];
#pragma unroll
        for (int mf = 0; mf < 4; ++mf)
#pragma unroll
          for (int nf = 0; nf < 4; ++nf)
            acc[mf][nf] = __builtin_amdgcn_mfma_f32_16x16x32_bf16(a[mf], b[nf], acc[mf][nf], 0, 0, 0);
      }
    }
  }

  // ---- epilogue: bias + exact gelu + gated 8-col reduce + atomic residual add ----
  const float* gp[3] = {nullptr, nullptr, nullptr};
  float*       hp[3] = {nullptr, nullptr, nullptr};
  int ld[3] = {0, 0, 0}, off[3] = {0, 0, 0};
  if (t == 0) {        // e_sh -> o_sh(g[8..15]), o_t1(g[8..15]), o_t2(g[8..15])
    gp[0] = g_sh; ld[0] = 24; off[0] = 8;  hp[0] = h;
    gp[1] = g_t1; ld[1] = 16; off[1] = 8;  hp[1] = h + (size_t)M_ * H_;
    gp[2] = g_t2; ld[2] = 16; off[2] = 8;  hp[2] = h + (size_t)2 * M_ * H_;
  } else if (t == 1) { // e_t1 -> o_sh(g[0..7]), o_t1(g[0..7])
    gp[0] = g_sh; ld[0] = 24; off[0] = 0;  hp[0] = h;
    gp[1] = g_t1; ld[1] = 16; off[1] = 0;  hp[1] = h + (size_t)M_ * H_;
  } else {             // e_t2 -> o_sh(g[16..23]), o_t2(g[0..7])
    gp[0] = g_sh; ld[0] = 24; off[0] = 16; hp[0] = h;
    gp[1] = g_t2; ld[1] = 16; off[1] = 0;  hp[1] = h + (size_t)2 * M_ * H_;
  }
  const float* be = b_exp_l + (size_t)t * N_;
  const int lr = lane & 15;
  const int e  = lane & 7;
#pragma unroll
  for (int mf = 0; mf < 4; ++mf) {
    const int r0 = m0 + wr * 64 + mf * 16 + ((lane >> 4) << 2);
#pragma unroll
    for (int nf = 0; nf < 4; ++nf) {
      const int n = n0 + wc * 64 + nf * 16 + lr;
      const float bias = be[n];
      float v[4];
#pragma unroll
      for (int r = 0; r < 4; ++r) v[r] = gelu_exact(acc[mf][nf][r] + bias);
      const int xg = (n0 + wc * 64 + nf * 16 + (lane & 8)) >> 3;
#pragma unroll
      for (int tg = 0; tg < 3; ++tg) {
        if (gp[tg] == nullptr) continue;   // uniform per block
        float w[4];
#pragma unroll
        for (int r = 0; r < 4; ++r)
          w[r] = v[r] * gp[tg][(size_t)(r0 + r) * ld[tg] + off[tg] + e];
#pragma unroll
        for (int r = 0; r < 4; ++r) {
          w[r] += __shfl_xor(w[r], 1);
          w[r] += __shfl_xor(w[r], 2);
          w[r] += __shfl_xor(w[r], 4);
        }
        if ((lane & 7) == 0) {
#pragma unroll
          for (int r = 0; r < 4; ++r)
            atomicAdd(&hp[tg][(size_t)(r0 + r) * H_ + xg], w[r]);
        }
      }
    }
  }
}

// --------------------------------------------------------------- output heads
__global__ __launch_bounds__(128) void heads(
    const float* __restrict__ h,
    const float* __restrict__ Wspan, const float* __restrict__ bspan,
    const float* __restrict__ Was,   const float* __restrict__ bas,
    const float* __restrict__ Wae,   const float* __restrict__ bae,
    float* __restrict__ out)
{
  const int row = blockIdx.x;
  __shared__ float s1[768], s2[768];
  const float* h1 = h + ((size_t)M_ + row) * H_;        // task1 tower
  const float* h2 = h + ((size_t)2 * M_ + row) * H_;    // task2 tower
  for (int i = threadIdx.x; i < 768; i += 128) { s1[i] = h1[i]; s2[i] = h2[i]; }
  __syncthreads();
  const int j = threadIdx.x;
  const float* W; const float* src; float bias; float* op; int ldw;
  if (j < 5)       { W = Wspan + j;      src = s1; bias = bspan[j];  op = out + (size_t)row * 5 + j;               ldw = 5;  }
  else if (j < 36) { W = Was + (j - 5);  src = s2; bias = bas[j-5];  op = out + 20480 + (size_t)row * 31 + (j-5);  ldw = 31; }
  else if (j < 67) { W = Wae + (j - 36); src = s2; bias = bae[j-36]; op = out + 147456 + (size_t)row * 31 + (j-36);ldw = 31; }
  else return;
  float acc = bias;
  for (int i = 0; i < 768; ++i) acc += src[i] * W[(size_t)i * ldw];
  *op = acc;
}

// ---------------------------------------------------------------------- launch
extern "C" void kernel_launch(void* const* d_in, const int* in_sizes, int n_in,
                              void* d_out, int out_size, void* d_ws, size_t ws_size,
                              hipStream_t stream) {
  (void)in_sizes; (void)n_in; (void)out_size; (void)ws_size;
  const float* share  = (const float*)d_in[0];
  const float* span   = (const float*)d_in[1];
  const float* attr   = (const float*)d_in[2];
  const float* ln_g   = (const float*)d_in[3];
  const float* ln_b   = (const float*)d_in[4];
  const float* W_exp  = (const float*)d_in[5];
  const float* b_exp  = (const float*)d_in[6];
  const float* Wg_sh  = (const float*)d_in[7];
  const float* bg_sh  = (const float*)d_in[8];
  const float* Wg_t1  = (const float*)d_in[9];
  const float* bg_t1  = (const float*)d_in[10];
  const float* Wg_t2  = (const float*)d_in[11];
  const float* bg_t2  = (const float*)d_in[12];
  const float* W_span = (const float*)d_in[13];
  const float* b_span = (const float*)d_in[14];
  const float* W_as   = (const float*)d_in[15];
  const float* b_as   = (const float*)d_in[16];
  const float* W_ae   = (const float*)d_in[17];
  const float* b_ae   = (const float*)d_in[18];

  // workspace layout (~114.2 MB)
  char* ws = (char*)d_ws;
  short* Wb = (short*)ws;                                  // [L][3][N][K] bf16
  size_t o = (size_t)L_ * 3 * N_ * K_ * 2;                 // 56,623,104
  short* xs = (short*)(ws + o); o += (size_t)3 * M_ * K_ * 2;   // 18,874,368
  float* h  = (float*)(ws + o); o += (size_t)3 * M_ * H_ * 4;   // 37,748,736
  float* gates = (float*)(ws + o);                         // 917,504

  copy3<<<9216, 256, 0, stream>>>((const float4*)share, (const float4*)span,
                                  (const float4*)attr, (float4*)h);
  conv_w<<<dim3(96, 12, 6), 256, 0, stream>>>(W_exp, Wb);

  for (int l = 0; l < L_; ++l) {
    ln_gates<<<3072, 256, 0, stream>>>(
        h, xs,
        ln_g + (size_t)l * 3 * H_, ln_b + (size_t)l * 3 * H_,
        Wg_sh + (size_t)l * H_ * 24, bg_sh + (size_t)l * 24,
        Wg_t1 + (size_t)l * H_ * 16, bg_t1 + (size_t)l * 16,
        Wg_t2 + (size_t)l * H_ * 16, bg_t2 + (size_t)l * 16,
        gates);
    expert_gemm<<<dim3(32, 48, 3), 256, 0, stream>>>(
        xs, Wb + (size_t)l * 3 * N_ * K_,
        b_exp + (size_t)l * 3 * N_,
        gates, gates + (size_t)M_ * 24, gates + (size_t)M_ * 24 + (size_t)M_ * 16,
        h);
  }

  heads<<<4096, 128, 0, stream>>>(h, W_span, b_span, W_as, b_as, W_ae, b_ae,
                                  (float*)d_out);
}

// Round 2
// 672.999 us; speedup vs baseline: 2.2288x; 2.2288x over previous
//
#include <hip/hip_runtime.h>
#include <hip/hip_bf16.h>
#include <math.h>

#define M_ 4096            // B*S
#define N_ 6144            // H*E
#define K_ 768             // H
#define H_ 768
#define L_ 2

using bf16x8 = __attribute__((ext_vector_type(8))) short;
using f32x4  = __attribute__((ext_vector_type(4))) float;

__device__ __forceinline__ unsigned short f2bf(float f) {
  unsigned int u = __builtin_bit_cast(unsigned int, f);
  u += 0x7FFFu + ((u >> 16) & 1u);
  return (unsigned short)(u >> 16);
}

__device__ __forceinline__ float bf2f(unsigned short u) {
  return __builtin_bit_cast(float, (unsigned int)u << 16);
}

// tanh-form GELU: x*sigmoid(1.59576912x + 0.07135482x^3); max |err| vs exact ~3e-4
__device__ __forceinline__ float gelu_fast(float x) {
  float u2 = x * (1.5957691f + 0.07135481f * x * x);
  return x / (1.f + __expf(-u2));
}

// async global->LDS, 16B per lane. LDS dest must be wave-uniform base; HW adds lane*16.
__device__ __forceinline__ void gload_lds16(const void* g, void* l) {
  __builtin_amdgcn_global_load_lds(
      (__attribute__((address_space(1))) unsigned int*)(uintptr_t)g,
      (__attribute__((address_space(3))) unsigned int*)(unsigned int)(uintptr_t)l,
      16, 0, 0);
}

// ---------------------------------------------------------------- prep kernels
__global__ __launch_bounds__(256) void copy3(const float4* __restrict__ a,
                                             const float4* __restrict__ b,
                                             const float4* __restrict__ c,
                                             float4* __restrict__ h) {
  const int n4 = M_ * H_ / 4;  // 786432
  int i = blockIdx.x * 256 + threadIdx.x;
  if (i < n4) h[i] = a[i];
  else if (i < 2 * n4) h[i] = b[i - n4];
  else h[i] = c[i - 2 * n4];
}

// W_exp layer-slab [3][768(k)][6144(n)] fp32 -> Wb [3][6144(n)][768(k)] bf16
__global__ __launch_bounds__(256) void conv_w(const float* __restrict__ W,
                                              short* __restrict__ Wb) {
  __shared__ float tile[64][65];
  const int z = blockIdx.z;            // tower
  const int n0 = blockIdx.x * 64;
  const int k0 = blockIdx.y * 64;
  const size_t inb  = (size_t)z * K_ * N_;
  const size_t outb = (size_t)z * N_ * K_;
  const int tid = threadIdx.x;
  const int c = tid & 63;
  const int r = tid >> 6;              // 0..3
#pragma unroll
  for (int p = 0; p < 16; ++p) {
    const int kk = p * 4 + r;
    tile[c][kk] = W[inb + (size_t)(k0 + kk) * N_ + n0 + c];
  }
  __syncthreads();
#pragma unroll
  for (int p = 0; p < 16; ++p) {
    const int nn = p * 4 + r;
    Wb[outb + (size_t)(n0 + nn) * K_ + k0 + c] = (short)f2bf(tile[nn][c]);
  }
}

// ------------------------------- LN + gates (1 wave/row), fused partial-combine
// part streams: s0:t0->sh  s1:t0->t1  s2:t0->t2  s3:t1->sh  s4:t1->t1  s5:t2->sh  s6:t2->t2
__global__ __launch_bounds__(256, 4) void ln_gates(
    float* __restrict__ h,                  // [3][M][H] (residual state, updated when have)
    const unsigned short* __restrict__ part,// [7][M][H] bf16
    int have,
    short* __restrict__ xs,                 // [3][M][H] bf16 out
    const float* __restrict__ ln_g,         // [3][H]
    const float* __restrict__ ln_b,
    const float* __restrict__ Wg_sh, const float* __restrict__ bg_sh,
    const float* __restrict__ Wg_t1, const float* __restrict__ bg_t1,
    const float* __restrict__ Wg_t2, const float* __restrict__ bg_t2,
    float* __restrict__ gates)              // g_sh [M][24]; g_t1 [M][16]; g_t2 [M][16]
{
  const int gw   = blockIdx.x * 4 + (threadIdx.x >> 6);
  const int t    = gw >> 12;
  const int row  = gw & 4095;
  const int lane = threadIdx.x & 63;
  float* hrow = h + ((size_t)t * M_ + row) * H_;

  const size_t MH = (size_t)M_ * H_;
  const unsigned short *pa = nullptr, *pb = nullptr, *pc = nullptr;
  if (have) {
    if (t == 0)      { pa = part + (size_t)row * H_;            pb = part + 3 * MH + (size_t)row * H_; pc = part + 5 * MH + (size_t)row * H_; }
    else if (t == 1) { pa = part + 1 * MH + (size_t)row * H_;   pb = part + 4 * MH + (size_t)row * H_; }
    else             { pa = part + 2 * MH + (size_t)row * H_;   pb = part + 6 * MH + (size_t)row * H_; }
  }

  float x[12];
  float sum = 0.f, ss = 0.f;
#pragma unroll
  for (int q = 0; q < 3; ++q) {
    const int o = q * 256 + lane * 4;
    float4 v = *(const float4*)(hrow + o);
    if (have) {
      ushort4 a4 = *(const ushort4*)(pa + o);
      ushort4 b4 = *(const ushort4*)(pb + o);
      v.x += bf2f(a4.x) + bf2f(b4.x);
      v.y += bf2f(a4.y) + bf2f(b4.y);
      v.z += bf2f(a4.z) + bf2f(b4.z);
      v.w += bf2f(a4.w) + bf2f(b4.w);
      if (t == 0) {
        ushort4 c4 = *(const ushort4*)(pc + o);
        v.x += bf2f(c4.x); v.y += bf2f(c4.y); v.z += bf2f(c4.z); v.w += bf2f(c4.w);
      }
      *(float4*)(hrow + o) = v;   // residual state write-back
    }
    x[q * 4 + 0] = v.x; x[q * 4 + 1] = v.y; x[q * 4 + 2] = v.z; x[q * 4 + 3] = v.w;
    sum += v.x + v.y + v.z + v.w;
    ss  += v.x * v.x + v.y * v.y + v.z * v.z + v.w * v.w;
  }
#pragma unroll
  for (int m = 1; m < 64; m <<= 1) { sum += __shfl_xor(sum, m); ss += __shfl_xor(ss, m); }
  const float mean = sum * (1.f / 768.f);
  float var = ss * (1.f / 768.f) - mean * mean;
  var = var < 0.f ? 0.f : var;
  const float rstd = rsqrtf(var + 1e-5f);

  const float* ga = ln_g + (size_t)t * H_;
  const float* be = ln_b + (size_t)t * H_;
  short* xrow = xs + ((size_t)t * M_ + row) * H_;
#pragma unroll
  for (int q = 0; q < 3; ++q) {
    float4 g4 = *(const float4*)(ga + q * 256 + lane * 4);
    float4 b4 = *(const float4*)(be + q * 256 + lane * 4);
    float y0 = g4.x * (x[q * 4 + 0] - mean) * rstd + b4.x;
    float y1 = g4.y * (x[q * 4 + 1] - mean) * rstd + b4.y;
    float y2 = g4.z * (x[q * 4 + 2] - mean) * rstd + b4.z;
    float y3 = g4.w * (x[q * 4 + 3] - mean) * rstd + b4.w;
    x[q * 4 + 0] = y0; x[q * 4 + 1] = y1; x[q * 4 + 2] = y2; x[q * 4 + 3] = y3;
    ushort4 st; st.x = f2bf(y0); st.y = f2bf(y1); st.z = f2bf(y2); st.w = f2bf(y3);
    *(ushort4*)(xrow + q * 256 + lane * 4) = st;
  }

  // ---- gate logits ----
  const float* Wg; const float* bg;
  if (t == 0)      { Wg = Wg_sh; bg = bg_sh; }
  else if (t == 1) { Wg = Wg_t1; bg = bg_t1; }
  else             { Wg = Wg_t2; bg = bg_t2; }
  const int NG = (t == 0) ? 24 : 16;

  float p[24];
#pragma unroll
  for (int j = 0; j < 24; ++j) p[j] = 0.f;
#pragma unroll
  for (int q = 0; q < 3; ++q)
#pragma unroll
    for (int jj = 0; jj < 4; ++jj) {
      const int i = q * 256 + lane * 4 + jj;
      const float xv = x[q * 4 + jj];
      const float* wrow = Wg + (size_t)i * NG;
#pragma unroll
      for (int j = 0; j < 16; ++j) p[j] += xv * wrow[j];
      if (t == 0) {
#pragma unroll
        for (int j = 16; j < 24; ++j) p[j] += xv * wrow[j];
      }
    }
#pragma unroll
  for (int j = 0; j < 16; ++j)
#pragma unroll
    for (int m = 1; m < 64; m <<= 1) p[j] += __shfl_xor(p[j], m);
  if (t == 0) {
#pragma unroll
    for (int j = 16; j < 24; ++j)
#pragma unroll
      for (int m = 1; m < 64; m <<= 1) p[j] += __shfl_xor(p[j], m);
  }
  float mx = -1e30f;
#pragma unroll
  for (int j = 0; j < 16; ++j) { p[j] += bg[j]; mx = fmaxf(mx, p[j]); }
  if (t == 0) {
#pragma unroll
    for (int j = 16; j < 24; ++j) { p[j] += bg[j]; mx = fmaxf(mx, p[j]); }
  }
  float s = 0.f;
#pragma unroll
  for (int j = 0; j < 16; ++j) { p[j] = __expf(p[j] - mx); s += p[j]; }
  if (t == 0) {
#pragma unroll
    for (int j = 16; j < 24; ++j) { p[j] = __expf(p[j] - mx); s += p[j]; }
  }
  const float inv = 1.f / s;

  float* grow;
  if (t == 0)      grow = gates + (size_t)row * 24;
  else if (t == 1) grow = gates + (size_t)M_ * 24 + (size_t)row * 16;
  else             grow = gates + (size_t)M_ * 24 + (size_t)M_ * 16 + (size_t)row * 16;
  if (lane == 0) {
#pragma unroll
    for (int j = 0; j < 16; ++j) grow[j] = p[j] * inv;
    if (t == 0) {
#pragma unroll
      for (int j = 16; j < 24; ++j) grow[j] = p[j] * inv;
    }
  }
}

// ---------------- gated 8-expert reduce-scatter + bf16 partial store (per mf, per stream)
__device__ __forceinline__ void reduce_store(const float vv[4][4],
                                             const float* __restrict__ gp, int ldg, int offg,
                                             unsigned short* __restrict__ pp,
                                             int rbase, int xbase, int lane) {
  const int e = lane & 7;
  float gv[4];
#pragma unroll
  for (int r = 0; r < 4; ++r) gv[r] = gp[(size_t)(rbase + r) * ldg + offg + e];
  float s[16];
#pragma unroll
  for (int nf = 0; nf < 4; ++nf)
#pragma unroll
    for (int r = 0; r < 4; ++r) s[nf * 4 + r] = vv[nf][r] * gv[r];
  // reduce-scatter over 8-lane groups (xor 4,2,1): 16 scalars -> 2 per lane
  float t8[8];
#pragma unroll
  for (int i = 0; i < 8; ++i) {
    float lo = s[i], hi = s[i + 8];
    float send = (lane & 4) ? lo : hi;
    float recv = __shfl_xor(send, 4);
    t8[i] = (lane & 4) ? hi + recv : lo + recv;
  }
  float t4[4];
#pragma unroll
  for (int i = 0; i < 4; ++i) {
    float lo = t8[i], hi = t8[i + 4];
    float send = (lane & 2) ? lo : hi;
    float recv = __shfl_xor(send, 2);
    t4[i] = (lane & 2) ? hi + recv : lo + recv;
  }
  float t2[2];
#pragma unroll
  for (int i = 0; i < 2; ++i) {
    float lo = t4[i], hi = t4[i + 2];
    float send = (lane & 1) ? lo : hi;
    float recv = __shfl_xor(send, 1);
    t2[i] = (lane & 1) ? hi + recv : lo + recv;
  }
  // lane holds idx = {b3,b2,b1,k}: b3=(lane>>2)&1, b2=(lane>>1)&1, b1=lane&1; idx=nf*4+r
  const int nf  = (((lane >> 2) & 1) << 1) | ((lane >> 1) & 1);
  const int rlo = (lane & 1) << 1;
  const int x   = xbase + nf * 2 + ((lane >> 3) & 1);
  pp[(size_t)(rbase + rlo)     * H_ + x] = f2bf(t2[0]);
  pp[(size_t)(rbase + rlo + 1) * H_ + x] = f2bf(t2[1]);
}

// ------------------------------------------------ expert GEMM + gelu + gated combine
__global__ __launch_bounds__(256, 2) void expert_gemm(
    const short* __restrict__ xs,      // [3][M][K]
    const short* __restrict__ Wb,      // [3][N][K] this layer
    const float* __restrict__ b_exp_l, // [3][N]
    const float* __restrict__ g_sh,    // [M][24]
    const float* __restrict__ g_t1,    // [M][16]
    const float* __restrict__ g_t2,    // [M][16]
    unsigned short* __restrict__ part) // [7][M][H] bf16
{
  const int t  = blockIdx.z;
  const int m0 = blockIdx.x * 128;
  const int n0 = blockIdx.y * 128;
  const short* A  = xs + (size_t)t * M_ * K_;
  const short* Bt = Wb + (size_t)t * N_ * K_;

  __shared__ short As[128 * 64];
  __shared__ short Bs[128 * 64];

  const int tid  = threadIdx.x;
  const int wave = tid >> 6;
  const int lane = tid & 63;
  const int wr = wave >> 1, wc = wave & 1;

  f32x4 acc[4][4];
#pragma unroll
  for (int i = 0; i < 4; ++i)
#pragma unroll
    for (int j = 0; j < 4; ++j) acc[i][j] = (f32x4){0.f, 0.f, 0.f, 0.f};

  const int lr8 = lane >> 3;
  const int seg = lane & 7;

  for (int kt = 0; kt < K_ / 64; ++kt) {
    __syncthreads();
    const int k0 = kt * 64;
#pragma unroll
    for (int q = 0; q < 4; ++q) {
      const int rowbase = wave * 32 + q * 8;
      gload_lds16(A  + (size_t)(m0 + rowbase + lr8) * K_ + k0 + seg * 8, &As[rowbase * 64]);
      gload_lds16(Bt + (size_t)(n0 + rowbase + lr8) * K_ + k0 + seg * 8, &Bs[rowbase * 64]);
    }
    __syncthreads();
    {
      const int lr = lane & 15;
#pragma unroll
      for (int ks = 0; ks < 2; ++ks) {
        const int lk = ks * 32 + ((lane >> 4) << 3);
        bf16x8 a[4], b[4];
#pragma unroll
        for (int mf = 0; mf < 4; ++mf)
          a[mf] = *(const bf16x8*)&As[(wr * 64 + mf * 16 + lr) * 64 + lk];
#pragma unroll
        for (int nf = 0; nf < 4; ++nf)
          b[nf] = *(const bf16x8*)&Bs[(wc * 64 + nf * 16 + lr) * 64 + lk];
#pragma unroll
        for (int mf = 0; mf < 4; ++mf)
#pragma unroll
          for (int nf = 0; nf < 4; ++nf)
            acc[mf][nf] = __builtin_amdgcn_mfma_f32_16x16x32_bf16(a[mf], b[nf], acc[mf][nf], 0, 0, 0);
      }
    }
  }

  // ---- epilogue: bias + fast-gelu + gated reduce-scatter + bf16 partial stores ----
  const size_t MH = (size_t)M_ * H_;
  const float *gpA, *gpB, *gpC = nullptr;
  unsigned short *ppA, *ppB, *ppC = nullptr;
  int ldA, ldB, ldC = 16, offA, offB, offC = 0, ntg;
  if (t == 0) {
    gpA = g_sh; ldA = 24; offA = 8; ppA = part;
    gpB = g_t1; ldB = 16; offB = 8; ppB = part + 1 * MH;
    gpC = g_t2; ldC = 16; offC = 8; ppC = part + 2 * MH; ntg = 3;
  } else if (t == 1) {
    gpA = g_sh; ldA = 24; offA = 0; ppA = part + 3 * MH;
    gpB = g_t1; ldB = 16; offB = 0; ppB = part + 4 * MH; ntg = 2;
  } else {
    gpA = g_sh; ldA = 24; offA = 16; ppA = part + 5 * MH;
    gpB = g_t2; ldB = 16; offB = 0;  ppB = part + 6 * MH; ntg = 2;
  }
  const float* be = b_exp_l + (size_t)t * N_;
  const int xbase = (n0 + wc * 64) >> 3;
#pragma unroll
  for (int mf = 0; mf < 4; ++mf) {
    const int rbase = m0 + wr * 64 + mf * 16 + ((lane >> 4) << 2);
    float vv[4][4];
#pragma unroll
    for (int nf = 0; nf < 4; ++nf) {
      const int n = n0 + wc * 64 + nf * 16 + (lane & 15);
      const float bias = be[n];
#pragma unroll
      for (int r = 0; r < 4; ++r) vv[nf][r] = gelu_fast(acc[mf][nf][r] + bias);
    }
    reduce_store(vv, gpA, ldA, offA, ppA, rbase, xbase, lane);
    reduce_store(vv, gpB, ldB, offB, ppB, rbase, xbase, lane);
    if (ntg == 3) reduce_store(vv, gpC, ldC, offC, ppC, rbase, xbase, lane);
  }
}

// --------------------------------------------------------------- output heads
__global__ __launch_bounds__(128) void heads(
    const float* __restrict__ h,
    const unsigned short* __restrict__ part,
    const float* __restrict__ Wspan, const float* __restrict__ bspan,
    const float* __restrict__ Was,   const float* __restrict__ bas,
    const float* __restrict__ Wae,   const float* __restrict__ bae,
    float* __restrict__ out)
{
  const int row = blockIdx.x;
  __shared__ float s1[768], s2[768];
  const size_t MH = (size_t)M_ * H_;
  const float* h1 = h + ((size_t)M_ + row) * H_;
  const float* h2 = h + ((size_t)2 * M_ + row) * H_;
  const unsigned short* p1a = part + 1 * MH + (size_t)row * H_;
  const unsigned short* p1b = part + 4 * MH + (size_t)row * H_;
  const unsigned short* p2a = part + 2 * MH + (size_t)row * H_;
  const unsigned short* p2b = part + 6 * MH + (size_t)row * H_;
  for (int i = threadIdx.x; i < 768; i += 128) {
    s1[i] = h1[i] + bf2f(p1a[i]) + bf2f(p1b[i]);
    s2[i] = h2[i] + bf2f(p2a[i]) + bf2f(p2b[i]);
  }
  __syncthreads();
  const int j = threadIdx.x;
  const float* W; const float* src; float bias; float* op; int ldw;
  if (j < 5)       { W = Wspan + j;      src = s1; bias = bspan[j];  op = out + (size_t)row * 5 + j;                ldw = 5;  }
  else if (j < 36) { W = Was + (j - 5);  src = s2; bias = bas[j-5];  op = out + 20480 + (size_t)row * 31 + (j-5);   ldw = 31; }
  else if (j < 67) { W = Wae + (j - 36); src = s2; bias = bae[j-36]; op = out + 147456 + (size_t)row * 31 + (j-36); ldw = 31; }
  else return;
  float acc = bias;
  for (int i = 0; i < 768; ++i) acc += src[i] * W[(size_t)i * ldw];
  *op = acc;
}

// ---------------------------------------------------------------------- launch
extern "C" void kernel_launch(void* const* d_in, const int* in_sizes, int n_in,
                              void* d_out, int out_size, void* d_ws, size_t ws_size,
                              hipStream_t stream) {
  (void)in_sizes; (void)n_in; (void)out_size; (void)ws_size;
  const float* share  = (const float*)d_in[0];
  const float* span   = (const float*)d_in[1];
  const float* attr   = (const float*)d_in[2];
  const float* ln_g   = (const float*)d_in[3];
  const float* ln_b   = (const float*)d_in[4];
  const float* W_exp  = (const float*)d_in[5];
  const float* b_exp  = (const float*)d_in[6];
  const float* Wg_sh  = (const float*)d_in[7];
  const float* bg_sh  = (const float*)d_in[8];
  const float* Wg_t1  = (const float*)d_in[9];
  const float* bg_t1  = (const float*)d_in[10];
  const float* Wg_t2  = (const float*)d_in[11];
  const float* bg_t2  = (const float*)d_in[12];
  const float* W_span = (const float*)d_in[13];
  const float* b_span = (const float*)d_in[14];
  const float* W_as   = (const float*)d_in[15];
  const float* b_as   = (const float*)d_in[16];
  const float* W_ae   = (const float*)d_in[17];
  const float* b_ae   = (const float*)d_in[18];

  // workspace layout (~130 MB)
  char* ws = (char*)d_ws;
  short* Wb = (short*)ws;                                        // [3][N][K] bf16 (per layer)
  size_t o = (size_t)3 * N_ * K_ * 2;                            // 28,311,552
  short* xs = (short*)(ws + o); o += (size_t)3 * M_ * K_ * 2;    // 18,874,368
  float* h  = (float*)(ws + o); o += (size_t)3 * M_ * H_ * 4;    // 37,748,736
  float* gates = (float*)(ws + o); o += (size_t)M_ * (24 + 16 + 16) * 4;  // 917,504
  unsigned short* part = (unsigned short*)(ws + o);              // [7][M][H] bf16: 44,040,192

  copy3<<<9216, 256, 0, stream>>>((const float4*)share, (const float4*)span,
                                  (const float4*)attr, (float4*)h);

  for (int l = 0; l < L_; ++l) {
    conv_w<<<dim3(96, 12, 3), 256, 0, stream>>>(W_exp + (size_t)l * 3 * K_ * N_, Wb);
    ln_gates<<<3072, 256, 0, stream>>>(
        h, part, (l > 0) ? 1 : 0, xs,
        ln_g + (size_t)l * 3 * H_, ln_b + (size_t)l * 3 * H_,
        Wg_sh + (size_t)l * H_ * 24, bg_sh + (size_t)l * 24,
        Wg_t1 + (size_t)l * H_ * 16, bg_t1 + (size_t)l * 16,
        Wg_t2 + (size_t)l * H_ * 16, bg_t2 + (size_t)l * 16,
        gates);
    expert_gemm<<<dim3(32, 48, 3), 256, 0, stream>>>(
        xs, Wb, b_exp + (size_t)l * 3 * N_,
        gates, gates + (size_t)M_ * 24, gates + (size_t)M_ * 24 + (size_t)M_ * 16,
        part);
  }

  heads<<<4096, 128, 0, stream>>>(h, part, W_span, b_span, W_as, b_as, W_ae, b_ae,
                                  (float*)d_out);
}

// Round 3
// 670.214 us; speedup vs baseline: 2.2380x; 1.0042x over previous
//
#include <hip/hip_runtime.h>
#include <hip/hip_bf16.h>
#include <math.h>

#define M_ 4096            // B*S
#define N_ 6144            // H*E
#define K_ 768             // H
#define H_ 768
#define L_ 2
#define NT 24              // K-tiles of BK=32

using bf16x8 = __attribute__((ext_vector_type(8))) short;
using f32x4  = __attribute__((ext_vector_type(4))) float;

__device__ __forceinline__ unsigned short f2bf(float f) {
  unsigned int u = __builtin_bit_cast(unsigned int, f);
  u += 0x7FFFu + ((u >> 16) & 1u);
  return (unsigned short)(u >> 16);
}

__device__ __forceinline__ float bf2f(unsigned short u) {
  return __builtin_bit_cast(float, (unsigned int)u << 16);
}

// tanh-form GELU: x*sigmoid(1.59576912x + 0.07135482x^3); max |err| vs exact ~3e-4
__device__ __forceinline__ float gelu_fast(float x) {
  float u2 = x * (1.5957691f + 0.07135481f * x * x);
  return x / (1.f + __expf(-u2));
}

// async global->LDS, 16B per lane. LDS dest must be wave-uniform base; HW adds lane*16.
__device__ __forceinline__ void gload_lds16(const void* g, void* l) {
  __builtin_amdgcn_global_load_lds(
      (__attribute__((address_space(1))) unsigned int*)(uintptr_t)g,
      (__attribute__((address_space(3))) unsigned int*)(unsigned int)(uintptr_t)l,
      16, 0, 0);
}

// W_exp layer-slab [3][768(k)][6144(n)] fp32 -> Wb [3][6144(n)][768(k)] bf16
__global__ __launch_bounds__(256) void conv_w(const float* __restrict__ W,
                                              short* __restrict__ Wb) {
  __shared__ float tile[64][65];
  const int z = blockIdx.z;            // tower
  const int n0 = blockIdx.x * 64;
  const int k0 = blockIdx.y * 64;
  const size_t inb  = (size_t)z * K_ * N_;
  const size_t outb = (size_t)z * N_ * K_;
  const int tid = threadIdx.x;
  const int c = tid & 63;
  const int r = tid >> 6;              // 0..3
#pragma unroll
  for (int p = 0; p < 16; ++p) {
    const int kk = p * 4 + r;
    tile[c][kk] = W[inb + (size_t)(k0 + kk) * N_ + n0 + c];
  }
  __syncthreads();
#pragma unroll
  for (int p = 0; p < 16; ++p) {
    const int nn = p * 4 + r;
    Wb[outb + (size_t)(n0 + nn) * K_ + k0 + c] = (short)f2bf(tile[nn][c]);
  }
}

// ------------------------------- LN + gates (1 wave/row), fused partial-combine
// part streams: s0:t0->sh s1:t0->t1 s2:t0->t2 s3:t1->sh s4:t1->t1 s5:t2->sh s6:t2->t2
// mode 0: x = raw input.  mode 1: x = raw input + layer-0 partials; write h = x.
__global__ __launch_bounds__(256, 4) void ln_gates(
    const float* __restrict__ in0, const float* __restrict__ in1,
    const float* __restrict__ in2,
    float* __restrict__ h,                  // [3][M][H] (written when mode==1)
    const unsigned short* __restrict__ part,// [7][M][H] bf16
    int mode,
    short* __restrict__ xs,                 // [3][M][H] bf16 out
    const float* __restrict__ ln_g,         // [3][H]
    const float* __restrict__ ln_b,
    const float* __restrict__ Wg_sh, const float* __restrict__ bg_sh,
    const float* __restrict__ Wg_t1, const float* __restrict__ bg_t1,
    const float* __restrict__ Wg_t2, const float* __restrict__ bg_t2,
    float* __restrict__ gates)              // g_sh [M][24]; g_t1 [M][16]; g_t2 [M][16]
{
  const int gw   = blockIdx.x * 4 + (threadIdx.x >> 6);
  const int t    = gw >> 12;
  const int row  = gw & 4095;
  const int lane = threadIdx.x & 63;
  const float* srow = (t == 0 ? in0 : (t == 1 ? in1 : in2)) + (size_t)row * H_;
  float* hrow = h + ((size_t)t * M_ + row) * H_;

  const size_t MH = (size_t)M_ * H_;
  const unsigned short *pa = nullptr, *pb = nullptr, *pc = nullptr;
  if (mode) {
    if (t == 0)      { pa = part + (size_t)row * H_;          pb = part + 3 * MH + (size_t)row * H_; pc = part + 5 * MH + (size_t)row * H_; }
    else if (t == 1) { pa = part + 1 * MH + (size_t)row * H_; pb = part + 4 * MH + (size_t)row * H_; }
    else             { pa = part + 2 * MH + (size_t)row * H_; pb = part + 6 * MH + (size_t)row * H_; }
  }

  float x[12];
  float sum = 0.f, ss = 0.f;
#pragma unroll
  for (int q = 0; q < 3; ++q) {
    const int o = q * 256 + lane * 4;
    float4 v = *(const float4*)(srow + o);
    if (mode) {
      ushort4 a4 = *(const ushort4*)(pa + o);
      ushort4 b4 = *(const ushort4*)(pb + o);
      v.x += bf2f(a4.x) + bf2f(b4.x);
      v.y += bf2f(a4.y) + bf2f(b4.y);
      v.z += bf2f(a4.z) + bf2f(b4.z);
      v.w += bf2f(a4.w) + bf2f(b4.w);
      if (t == 0) {
        ushort4 c4 = *(const ushort4*)(pc + o);
        v.x += bf2f(c4.x); v.y += bf2f(c4.y); v.z += bf2f(c4.z); v.w += bf2f(c4.w);
      }
      *(float4*)(hrow + o) = v;   // residual state write-back
    }
    x[q * 4 + 0] = v.x; x[q * 4 + 1] = v.y; x[q * 4 + 2] = v.z; x[q * 4 + 3] = v.w;
    sum += v.x + v.y + v.z + v.w;
    ss  += v.x * v.x + v.y * v.y + v.z * v.z + v.w * v.w;
  }
#pragma unroll
  for (int m = 1; m < 64; m <<= 1) { sum += __shfl_xor(sum, m); ss += __shfl_xor(ss, m); }
  const float mean = sum * (1.f / 768.f);
  float var = ss * (1.f / 768.f) - mean * mean;
  var = var < 0.f ? 0.f : var;
  const float rstd = rsqrtf(var + 1e-5f);

  const float* ga = ln_g + (size_t)t * H_;
  const float* be = ln_b + (size_t)t * H_;
  short* xrow = xs + ((size_t)t * M_ + row) * H_;
#pragma unroll
  for (int q = 0; q < 3; ++q) {
    float4 g4 = *(const float4*)(ga + q * 256 + lane * 4);
    float4 b4 = *(const float4*)(be + q * 256 + lane * 4);
    float y0 = g4.x * (x[q * 4 + 0] - mean) * rstd + b4.x;
    float y1 = g4.y * (x[q * 4 + 1] - mean) * rstd + b4.y;
    float y2 = g4.z * (x[q * 4 + 2] - mean) * rstd + b4.z;
    float y3 = g4.w * (x[q * 4 + 3] - mean) * rstd + b4.w;
    x[q * 4 + 0] = y0; x[q * 4 + 1] = y1; x[q * 4 + 2] = y2; x[q * 4 + 3] = y3;
    ushort4 st; st.x = f2bf(y0); st.y = f2bf(y1); st.z = f2bf(y2); st.w = f2bf(y3);
    *(ushort4*)(xrow + q * 256 + lane * 4) = st;
  }

  // ---- gate logits ----
  const float* Wg; const float* bg;
  if (t == 0)      { Wg = Wg_sh; bg = bg_sh; }
  else if (t == 1) { Wg = Wg_t1; bg = bg_t1; }
  else             { Wg = Wg_t2; bg = bg_t2; }
  const int NG = (t == 0) ? 24 : 16;

  float p[24];
#pragma unroll
  for (int j = 0; j < 24; ++j) p[j] = 0.f;
#pragma unroll
  for (int q = 0; q < 3; ++q)
#pragma unroll
    for (int jj = 0; jj < 4; ++jj) {
      const int i = q * 256 + lane * 4 + jj;
      const float xv = x[q * 4 + jj];
      const float* wrow = Wg + (size_t)i * NG;
#pragma unroll
      for (int j = 0; j < 16; ++j) p[j] += xv * wrow[j];
      if (t == 0) {
#pragma unroll
        for (int j = 16; j < 24; ++j) p[j] += xv * wrow[j];
      }
    }
#pragma unroll
  for (int j = 0; j < 16; ++j)
#pragma unroll
    for (int m = 1; m < 64; m <<= 1) p[j] += __shfl_xor(p[j], m);
  if (t == 0) {
#pragma unroll
    for (int j = 16; j < 24; ++j)
#pragma unroll
      for (int m = 1; m < 64; m <<= 1) p[j] += __shfl_xor(p[j], m);
  }
  float mx = -1e30f;
#pragma unroll
  for (int j = 0; j < 16; ++j) { p[j] += bg[j]; mx = fmaxf(mx, p[j]); }
  if (t == 0) {
#pragma unroll
    for (int j = 16; j < 24; ++j) { p[j] += bg[j]; mx = fmaxf(mx, p[j]); }
  }
  float s = 0.f;
#pragma unroll
  for (int j = 0; j < 16; ++j) { p[j] = __expf(p[j] - mx); s += p[j]; }
  if (t == 0) {
#pragma unroll
    for (int j = 16; j < 24; ++j) { p[j] = __expf(p[j] - mx); s += p[j]; }
  }
  const float inv = 1.f / s;

  float* grow;
  if (t == 0)      grow = gates + (size_t)row * 24;
  else if (t == 1) grow = gates + (size_t)M_ * 24 + (size_t)row * 16;
  else             grow = gates + (size_t)M_ * 24 + (size_t)M_ * 16 + (size_t)row * 16;
  if (lane == 0) {
#pragma unroll
    for (int j = 0; j < 16; ++j) grow[j] = p[j] * inv;
    if (t == 0) {
#pragma unroll
      for (int j = 16; j < 24; ++j) grow[j] = p[j] * inv;
    }
  }
}

// ---------------- gated 8-expert reduce-scatter + bf16 partial store (per mf, per stream)
__device__ __forceinline__ void reduce_store(const float vv[4][4],
                                             const float* __restrict__ gp, int ldg, int offg,
                                             unsigned short* __restrict__ pp,
                                             int rbase, int xbase, int lane) {
  const int e = lane & 7;
  float gv[4];
#pragma unroll
  for (int r = 0; r < 4; ++r) gv[r] = gp[(size_t)(rbase + r) * ldg + offg + e];
  float s[16];
#pragma unroll
  for (int nf = 0; nf < 4; ++nf)
#pragma unroll
    for (int r = 0; r < 4; ++r) s[nf * 4 + r] = vv[nf][r] * gv[r];
  float t8[8];
#pragma unroll
  for (int i = 0; i < 8; ++i) {
    float lo = s[i], hi = s[i + 8];
    float send = (lane & 4) ? lo : hi;
    float recv = __shfl_xor(send, 4);
    t8[i] = (lane & 4) ? hi + recv : lo + recv;
  }
  float t4[4];
#pragma unroll
  for (int i = 0; i < 4; ++i) {
    float lo = t8[i], hi = t8[i + 4];
    float send = (lane & 2) ? lo : hi;
    float recv = __shfl_xor(send, 2);
    t4[i] = (lane & 2) ? hi + recv : lo + recv;
  }
  float t2[2];
#pragma unroll
  for (int i = 0; i < 2; ++i) {
    float lo = t4[i], hi = t4[i + 2];
    float send = (lane & 1) ? lo : hi;
    float recv = __shfl_xor(send, 1);
    t2[i] = (lane & 1) ? hi + recv : lo + recv;
  }
  const int nf  = (((lane >> 2) & 1) << 1) | ((lane >> 1) & 1);
  const int rlo = (lane & 1) << 1;
  const int x   = xbase + nf * 2 + ((lane >> 3) & 1);
  pp[(size_t)(rbase + rlo)     * H_ + x] = f2bf(t2[0]);
  pp[(size_t)(rbase + rlo + 1) * H_ + x] = f2bf(t2[1]);
}

// ------------------------------------------------ expert GEMM (256x256, BK=32, 4-buf pipeline)
__global__ __launch_bounds__(512, 2) void expert_gemm(
    const short* __restrict__ xs,      // [3][M][K]
    const short* __restrict__ Wb,      // [3][N][K] this layer
    const float* __restrict__ b_exp_l, // [3][N]
    const float* __restrict__ g_sh,
    const float* __restrict__ g_t1,
    const float* __restrict__ g_t2,
    unsigned short* __restrict__ part) // [7][M][H] bf16
{
  __shared__ short lds[65536];  // 128 KiB: 4 bufs x (A 256x32 | B 256x32)

  // XCD-bijective swizzle: 1152 blocks, 8 XCDs, 144/XCD
  const int bid = blockIdx.x;
  const int swz = (bid & 7) * 144 + (bid >> 3);
  const int t  = swz / 384;
  const int rr = swz - t * 384;
  const int m0 = (rr / 24) * 256;
  const int n0 = (rr - (rr / 24) * 24) * 256;

  const short* A  = xs + (size_t)t * M_ * K_;
  const short* Bt = Wb + (size_t)t * N_ * K_;

  const int tid = threadIdx.x;
  const int w = tid >> 6, l = tid & 63;
  const int wr = w >> 2, wc = w & 3;    // 2 x 4 wave grid; per-wave 128 rows x 64 cols

  // staging: per K-tile each thread issues 4 gload_lds16 (2 A + 2 B).
  // LDS dest is linear; global source col is pre-swizzled (T2, rule #21):
  // phys slot (l&3) at row w*16+(l>>2) holds logical colgroup (l&3)^((row>>1)&3),
  // and (row>>1)&3 == (l>>3)&3.
  const int cswz = (((l & 3) ^ ((l >> 3) & 3)) << 3);          // shorts
  const short* Ag0 = A  + (size_t)(m0 + w * 16 + (l >> 2)) * K_ + cswz;
  const short* Bg0 = Bt + (size_t)(n0 + w * 16 + (l >> 2)) * K_ + cswz;
  const int ldsw = w * 512;                                    // wave-uniform dest (shorts)

  // frag-read offsets (swizzled): row = 16k + lr -> slot = c ^ ((lr>>1)&3)
  const int lr = l & 15, cg = l >> 4;
  const int roff = lr * 32 + (((cg ^ ((lr >> 1) & 3))) << 3);  // shorts

  f32x4 acc[8][4];
#pragma unroll
  for (int i = 0; i < 8; ++i)
#pragma unroll
    for (int j = 0; j < 4; ++j) acc[i][j] = (f32x4){0.f, 0.f, 0.f, 0.f};

  auto stageA = [&](int kt) {
    const int b2 = ((kt & 3) << 14) + ldsw;
    const short* a = Ag0 + kt * 32;
    gload_lds16(a,            &lds[b2]);
    gload_lds16(a + 128 * K_, &lds[b2 + 4096]);
  };
  auto stageB = [&](int kt) {
    const int b2 = ((kt & 3) << 14) + 8192 + ldsw;
    const short* b = Bg0 + kt * 32;
    gload_lds16(b,            &lds[b2]);
    gload_lds16(b + 128 * K_, &lds[b2 + 4096]);
  };

  // prologue: stage K-tiles 0..2 (12 loads), wait for K-tile 0 (8 younger remain)
  stageA(0); stageB(0);
  stageA(1); stageB(1);
  stageA(2); stageB(2);
  asm volatile("s_waitcnt vmcnt(8)" ::: "memory");
  __builtin_amdgcn_s_barrier();

  for (int kt = 0; kt < NT; ++kt) {
    const int base = (kt & 3) << 14;
    const short* lA = &lds[base + wr * 4096 + roff];
    const short* lB = &lds[base + 8192 + wc * 2048 + roff];

    // ---- phase A: ds_read 4A+4B, issue 2 staging loads, 16 MFMA (mf 0..3) ----
    bf16x8 a_[4], b_[4];
#pragma unroll
    for (int mf = 0; mf < 4; ++mf) a_[mf] = *(const bf16x8*)(lA + mf * 512);
#pragma unroll
    for (int nf = 0; nf < 4; ++nf) b_[nf] = *(const bf16x8*)(lB + nf * 512);
    if (kt < NT - 3) stageA(kt + 3);
    __builtin_amdgcn_s_barrier();
    __builtin_amdgcn_s_setprio(1);
#pragma unroll
    for (int mf = 0; mf < 4; ++mf)
#pragma unroll
      for (int nf = 0; nf < 4; ++nf)
        acc[mf][nf] = __builtin_amdgcn_mfma_f32_16x16x32_bf16(a_[mf], b_[nf], acc[mf][nf], 0, 0, 0);
    __builtin_amdgcn_s_setprio(0);
    __builtin_amdgcn_s_barrier();

    // ---- phase B: ds_read 4A, issue 2 staging loads, 16 MFMA (mf 4..7) ----
    bf16x8 a2_[4];
#pragma unroll
    for (int mf = 0; mf < 4; ++mf) a2_[mf] = *(const bf16x8*)(lA + (mf + 4) * 512);
    if (kt < NT - 3) stageB(kt + 3);
    __builtin_amdgcn_s_barrier();
    __builtin_amdgcn_s_setprio(1);
#pragma unroll
    for (int mf = 0; mf < 4; ++mf)
#pragma unroll
      for (int nf = 0; nf < 4; ++nf)
        acc[mf + 4][nf] = __builtin_amdgcn_mfma_f32_16x16x32_bf16(a2_[mf], b_[nf], acc[mf + 4][nf], 0, 0, 0);
    __builtin_amdgcn_s_setprio(0);

    // ---- K-tile boundary: counted vmcnt (T4) + lgkm drain, one barrier ----
    if (kt < NT - 1) {
      if (kt < NT - 3)       asm volatile("s_waitcnt vmcnt(8) lgkmcnt(0)" ::: "memory");
      else if (kt == NT - 3) asm volatile("s_waitcnt vmcnt(4) lgkmcnt(0)" ::: "memory");
      else                   asm volatile("s_waitcnt vmcnt(0) lgkmcnt(0)" ::: "memory");
      __builtin_amdgcn_s_barrier();
    }
  }

  // ---- epilogue: bias + fast-gelu + gated reduce-scatter + bf16 partial stores ----
  const size_t MH = (size_t)M_ * H_;
  const float *gpA, *gpB, *gpC = nullptr;
  unsigned short *ppA, *ppB, *ppC = nullptr;
  int ldA, ldB, ldC = 16, offA, offB, offC = 0, ntg;
  if (t == 0) {
    gpA = g_sh; ldA = 24; offA = 8; ppA = part;
    gpB = g_t1; ldB = 16; offB = 8; ppB = part + 1 * MH;
    gpC = g_t2; ldC = 16; offC = 8; ppC = part + 2 * MH; ntg = 3;
  } else if (t == 1) {
    gpA = g_sh; ldA = 24; offA = 0; ppA = part + 3 * MH;
    gpB = g_t1; ldB = 16; offB = 0; ppB = part + 4 * MH; ntg = 2;
  } else {
    gpA = g_sh; ldA = 24; offA = 16; ppA = part + 5 * MH;
    gpB = g_t2; ldB = 16; offB = 0;  ppB = part + 6 * MH; ntg = 2;
  }
  const float* be = b_exp_l + (size_t)t * N_;
  const int xbase = (n0 + wc * 64) >> 3;
#pragma unroll
  for (int mf = 0; mf < 8; ++mf) {
    const int rbase = m0 + wr * 128 + mf * 16 + ((l >> 4) << 2);
    float vv[4][4];
#pragma unroll
    for (int nf = 0; nf < 4; ++nf) {
      const int n = n0 + wc * 64 + nf * 16 + (l & 15);
      const float bias = be[n];
#pragma unroll
      for (int r = 0; r < 4; ++r) vv[nf][r] = gelu_fast(acc[mf][nf][r] + bias);
    }
    reduce_store(vv, gpA, ldA, offA, ppA, rbase, xbase, l);
    reduce_store(vv, gpB, ldB, offB, ppB, rbase, xbase, l);
    if (ntg == 3) reduce_store(vv, gpC, ldC, offC, ppC, rbase, xbase, l);
  }
}

// --------------------------------------------------------------- output heads
__global__ __launch_bounds__(128) void heads(
    const float* __restrict__ h,
    const unsigned short* __restrict__ part,
    const float* __restrict__ Wspan, const float* __restrict__ bspan,
    const float* __restrict__ Was,   const float* __restrict__ bas,
    const float* __restrict__ Wae,   const float* __restrict__ bae,
    float* __restrict__ out)
{
  const int row = blockIdx.x;
  __shared__ float s1[768], s2[768];
  const size_t MH = (size_t)M_ * H_;
  const float* h1 = h + ((size_t)M_ + row) * H_;
  const float* h2 = h + ((size_t)2 * M_ + row) * H_;
  const unsigned short* p1a = part + 1 * MH + (size_t)row * H_;
  const unsigned short* p1b = part + 4 * MH + (size_t)row * H_;
  const unsigned short* p2a = part + 2 * MH + (size_t)row * H_;
  const unsigned short* p2b = part + 6 * MH + (size_t)row * H_;
  for (int i = threadIdx.x; i < 768; i += 128) {
    s1[i] = h1[i] + bf2f(p1a[i]) + bf2f(p1b[i]);
    s2[i] = h2[i] + bf2f(p2a[i]) + bf2f(p2b[i]);
  }
  __syncthreads();
  const int j = threadIdx.x;
  const float* W; const float* src; float bias; float* op; int ldw;
  if (j < 5)       { W = Wspan + j;      src = s1; bias = bspan[j];  op = out + (size_t)row * 5 + j;                ldw = 5;  }
  else if (j < 36) { W = Was + (j - 5);  src = s2; bias = bas[j-5];  op = out + 20480 + (size_t)row * 31 + (j-5);   ldw = 31; }
  else if (j < 67) { W = Wae + (j - 36); src = s2; bias = bae[j-36]; op = out + 147456 + (size_t)row * 31 + (j-36); ldw = 31; }
  else return;
  float acc = bias;
  for (int i = 0; i < 768; ++i) acc += src[i] * W[(size_t)i * ldw];
  *op = acc;
}

// ---------------------------------------------------------------------- launch
extern "C" void kernel_launch(void* const* d_in, const int* in_sizes, int n_in,
                              void* d_out, int out_size, void* d_ws, size_t ws_size,
                              hipStream_t stream) {
  (void)in_sizes; (void)n_in; (void)out_size; (void)ws_size;
  const float* share  = (const float*)d_in[0];
  const float* span   = (const float*)d_in[1];
  const float* attr   = (const float*)d_in[2];
  const float* ln_g   = (const float*)d_in[3];
  const float* ln_b   = (const float*)d_in[4];
  const float* W_exp  = (const float*)d_in[5];
  const float* b_exp  = (const float*)d_in[6];
  const float* Wg_sh  = (const float*)d_in[7];
  const float* bg_sh  = (const float*)d_in[8];
  const float* Wg_t1  = (const float*)d_in[9];
  const float* bg_t1  = (const float*)d_in[10];
  const float* Wg_t2  = (const float*)d_in[11];
  const float* bg_t2  = (const float*)d_in[12];
  const float* W_span = (const float*)d_in[13];
  const float* b_span = (const float*)d_in[14];
  const float* W_as   = (const float*)d_in[15];
  const float* b_as   = (const float*)d_in[16];
  const float* W_ae   = (const float*)d_in[17];
  const float* b_ae   = (const float*)d_in[18];

  // workspace layout (~130 MB)
  char* ws = (char*)d_ws;
  short* Wb = (short*)ws;                                        // [3][N][K] bf16 (per layer)
  size_t o = (size_t)3 * N_ * K_ * 2;                            // 28,311,552
  short* xs = (short*)(ws + o); o += (size_t)3 * M_ * K_ * 2;    // 18,874,368
  float* h  = (float*)(ws + o); o += (size_t)3 * M_ * H_ * 4;    // 37,748,736
  float* gates = (float*)(ws + o); o += (size_t)M_ * (24 + 16 + 16) * 4;  // 917,504
  unsigned short* part = (unsigned short*)(ws + o);              // [7][M][H] bf16: 44,040,192

  for (int l = 0; l < L_; ++l) {
    conv_w<<<dim3(96, 12, 3), 256, 0, stream>>>(W_exp + (size_t)l * 3 * K_ * N_, Wb);
    ln_gates<<<3072, 256, 0, stream>>>(
        share, span, attr, h, part, l, xs,
        ln_g + (size_t)l * 3 * H_, ln_b + (size_t)l * 3 * H_,
        Wg_sh + (size_t)l * H_ * 24, bg_sh + (size_t)l * 24,
        Wg_t1 + (size_t)l * H_ * 16, bg_t1 + (size_t)l * 16,
        Wg_t2 + (size_t)l * H_ * 16, bg_t2 + (size_t)l * 16,
        gates);
    expert_gemm<<<1152, 512, 0, stream>>>(
        xs, Wb, b_exp + (size_t)l * 3 * N_,
        gates, gates + (size_t)M_ * 24, gates + (size_t)M_ * 24 + (size_t)M_ * 16,
        part);
  }

  heads<<<4096, 128, 0, stream>>>(h, part, W_span, b_span, W_as, b_as, W_ae, b_ae,
                                  (float*)d_out);
}